// Round 3
// baseline (28271.686 us; speedup 1.0000x reference)
//
#include <hip/hip_runtime.h>
#include <cstddef>

#define BB 256
#define SS 1024
#define VV 288
#define EE 100
#define HH 128
#define G4 512
#define TC 16

__device__ __forceinline__ float sigmoid_f(float x) {
    return __fdividef(1.0f, 1.0f + __expf(-x));
}
__device__ __forceinline__ float tanh_f(float x) {
    x = fminf(fmaxf(x, -15.0f), 15.0f);
    float e = __expf(2.0f * x);
    return __fdividef(e - 1.0f, e + 1.0f);
}

// table[v][j] = bih0[j]+bhh0[j] + sum_e emb[v][e] * Wih0[j][e]
__global__ __launch_bounds__(512) void proj_kernel(
    const float* __restrict__ emb, const float* __restrict__ Wih0,
    const float* __restrict__ bih0, const float* __restrict__ bhh0,
    float* __restrict__ table)
{
    __shared__ float er[EE];
    const int v = blockIdx.x;
    const int j = threadIdx.x;
    for (int e = j; e < EE; e += 512) er[e] = emb[v * EE + e];
    __syncthreads();
    float acc = bih0[j] + bhh0[j];
    const float* wr = Wih0 + j * EE;
#pragma unroll 4
    for (int e = 0; e < EE; e++) acc = fmaf(er[e], wr[e], acc);
    table[v * G4 + j] = acc;
}

// Layer 0: 512 threads, 1 gate per thread. Whh row j held in 32 float4 regs.
// amdgpu_waves_per_eu(2,2) -> 256-VGPR budget: no spill, no rematerialization.
__global__ __launch_bounds__(512)
__attribute__((amdgpu_waves_per_eu(2, 2)))
void lstm0_kernel(
    const int* __restrict__ text, const float* __restrict__ table,
    const float* __restrict__ Whh, float* __restrict__ hout)
{
    __shared__ float h_lds[HH];
    __shared__ float gact[G4];
    const int b = blockIdx.x;
    const int j = threadIdx.x;
    float4 w4[32];
    {
        const float4* wsrc = (const float4*)(Whh + (size_t)j * HH);
#pragma unroll
        for (int q = 0; q < 32; q++) w4[q] = wsrc[q];
    }
    if (j < HH) h_lds[j] = 0.0f;
    float c = 0.0f;
    const int quarter = j >> 7;
    const int* tptr = text + (size_t)b * SS;
    float gpre = table[(size_t)tptr[0] * G4 + j];
    __syncthreads();
    for (int t = 0; t < SS; t++) {
        float g = gpre;
        {
            const int tn = (t + 1 < SS) ? (t + 1) : (SS - 1);
            gpre = table[(size_t)tptr[tn] * G4 + j];  // prefetch next step (L2)
        }
        const float4* h4 = (const float4*)h_lds;
#pragma unroll 8
        for (int q = 0; q < 32; q++) {
            const float4 hv = h4[q];
            g = fmaf(hv.x, w4[q].x, g);
            g = fmaf(hv.y, w4[q].y, g);
            g = fmaf(hv.z, w4[q].z, g);
            g = fmaf(hv.w, w4[q].w, g);
        }
        gact[j] = (quarter == 2) ? tanh_f(g) : sigmoid_f(g);
        __syncthreads();
        if (j < HH) {
            const float gi = gact[j];
            const float gf = gact[j + HH];
            const float gg = gact[j + 2 * HH];
            const float go = gact[j + 3 * HH];
            c = fmaf(gf, c, gi * gg);
            const float hv = go * tanh_f(c);
            h_lds[j] = hv;
            hout[((size_t)t * BB + b) * HH + j] = hv;
        }
        __syncthreads();
    }
}

// Layers 1,2 in-place on hbuf. 512 threads, 1 gate per thread.
// Per 16-step chunk: input projection into REGISTER acc[16] (no xg LDS at
// all), Wih row j streamed from L1/L2 (same 512B per thread every chunk).
__global__ __launch_bounds__(512)
__attribute__((amdgpu_waves_per_eu(2, 2)))
void lstm12_kernel(
    const float* __restrict__ Wih,   // [512][128]
    const float* __restrict__ Whh,   // [512][128]
    const float* __restrict__ bih, const float* __restrict__ bhh,
    float* hbuf)
{
    __shared__ float h_lds[HH];
    __shared__ float gact[G4];
    __shared__ float xin[TC][HH];    // prev-layer h chunk, 8 KB
    const int b = blockIdx.x;
    const int j = threadIdx.x;
    float4 w4[32];
    {
        const float4* wsrc = (const float4*)(Whh + (size_t)j * HH);
#pragma unroll
        for (int q = 0; q < 32; q++) w4[q] = wsrc[q];
    }
    const float bj = bih[j] + bhh[j];
    const float4* wih4 = (const float4*)(Wih + (size_t)j * HH);
    if (j < HH) h_lds[j] = 0.0f;
    float c = 0.0f;
    const int quarter = j >> 7;
    __syncthreads();
    for (int t0 = 0; t0 < SS; t0 += TC) {
        // stage prev-layer h rows t0..t0+15 (read before in-place overwrite)
        {
            const int r = j >> 5, q = j & 31;
            ((float4*)&xin[r][0])[q] =
                ((const float4*)(hbuf + ((size_t)(t0 + r) * BB + b) * HH))[q];
        }
        __syncthreads();
        // ---- input projection for this chunk: acc[t] = Wih[j]·xin[t] + bj ----
        float acc[TC];
#pragma unroll
        for (int t = 0; t < TC; t++) acc[t] = bj;
#pragma unroll 4
        for (int kq = 0; kq < 32; kq++) {
            const float4 wv = wih4[kq];          // L1-resident after chunk 0
#pragma unroll
            for (int t = 0; t < TC; t++) {
                const float4 xv = ((const float4*)&xin[t][0])[kq];  // broadcast
                acc[t] = fmaf(xv.x, wv.x, acc[t]);
                acc[t] = fmaf(xv.y, wv.y, acc[t]);
                acc[t] = fmaf(xv.z, wv.z, acc[t]);
                acc[t] = fmaf(xv.w, wv.w, acc[t]);
            }
        }
        // ---- 16 recurrent steps; acc[tt] feeds directly from registers ----
        for (int tt = 0; tt < TC; tt++) {
            float g = acc[tt];
            const float4* h4 = (const float4*)h_lds;
#pragma unroll 8
            for (int q = 0; q < 32; q++) {
                const float4 hv = h4[q];
                g = fmaf(hv.x, w4[q].x, g);
                g = fmaf(hv.y, w4[q].y, g);
                g = fmaf(hv.z, w4[q].z, g);
                g = fmaf(hv.w, w4[q].w, g);
            }
            gact[j] = (quarter == 2) ? tanh_f(g) : sigmoid_f(g);
            __syncthreads();
            if (j < HH) {
                const float gi = gact[j];
                const float gf = gact[j + HH];
                const float gg = gact[j + 2 * HH];
                const float go = gact[j + 3 * HH];
                c = fmaf(gf, c, gi * gg);
                const float hv = go * tanh_f(c);
                h_lds[j] = hv;
                hbuf[((size_t)(t0 + tt) * BB + b) * HH + j] = hv;
            }
            __syncthreads();
        }
    }
}

// FC head: out[m][n] = dot(h[m], fcW[n]) + fcb[n]; M=262144, N=288, K=128
// grid = (9 n-tiles, 4096 m-tiles): n-tiles sharing an A-tile are
// dispatch-adjacent -> A read from HBM once, not 9x.
__global__ __launch_bounds__(256) void fc_kernel(
    const float* __restrict__ hbuf, const float* __restrict__ fcW,
    const float* __restrict__ fcb, float* __restrict__ out)
{
    __shared__ float Ash[128][68];
    __shared__ float Bsh[32][132];
    const int tid = threadIdx.x;
    const size_t mb = (size_t)blockIdx.y * 64;
    const int nb = blockIdx.x * 32;
#pragma unroll
    for (int p = 0; p < 8; p++) {
        const int fi = tid + p * 256;
        const int m = fi >> 5, k4 = fi & 31;
        float4 v = ((const float4*)(hbuf + (mb + m) * HH))[k4];
        Ash[k4*4+0][m] = v.x;
        Ash[k4*4+1][m] = v.y;
        Ash[k4*4+2][m] = v.z;
        Ash[k4*4+3][m] = v.w;
    }
#pragma unroll
    for (int p = 0; p < 4; p++) {
        const int fi = tid + p * 256;
        const int n = fi >> 5, k4 = fi & 31;
        ((float4*)&Bsh[n][0])[k4] = ((const float4*)(fcW + (size_t)(nb + n) * HH))[k4];
    }
    __syncthreads();
    const int tni = tid & 15, tmi = tid >> 4;
    const int m0 = tmi * 4, n0 = tni * 2;
    float a00=0,a01=0,a10=0,a11=0,a20=0,a21=0,a30=0,a31=0;
#pragma unroll 8
    for (int k = 0; k < 128; k++) {
        const float4 av = *((const float4*)&Ash[k][m0]);
        const float b0v = Bsh[n0][k], b1v = Bsh[n0+1][k];
        a00 = fmaf(av.x, b0v, a00); a01 = fmaf(av.x, b1v, a01);
        a10 = fmaf(av.y, b0v, a10); a11 = fmaf(av.y, b1v, a11);
        a20 = fmaf(av.z, b0v, a20); a21 = fmaf(av.z, b1v, a21);
        a30 = fmaf(av.w, b0v, a30); a31 = fmaf(av.w, b1v, a31);
    }
    const float c0 = fcb[nb + n0], c1 = fcb[nb + n0 + 1];
    float* o0 = out + (mb + m0 + 0) * VV + nb + n0;
    float* o1 = out + (mb + m0 + 1) * VV + nb + n0;
    float* o2 = out + (mb + m0 + 2) * VV + nb + n0;
    float* o3 = out + (mb + m0 + 3) * VV + nb + n0;
    *((float2*)o0) = make_float2(a00 + c0, a01 + c1);
    *((float2*)o1) = make_float2(a10 + c0, a11 + c1);
    *((float2*)o2) = make_float2(a20 + c0, a21 + c1);
    *((float2*)o3) = make_float2(a30 + c0, a31 + c1);
}

extern "C" void kernel_launch(void* const* d_in, const int* in_sizes, int n_in,
                              void* d_out, int out_size, void* d_ws, size_t ws_size,
                              hipStream_t stream)
{
    (void)in_sizes; (void)n_in; (void)out_size; (void)ws_size;
    const int*   text = (const int*)  d_in[0];
    const float* emb  = (const float*)d_in[1];
    const float* fcW  = (const float*)d_in[2];
    const float* fcb  = (const float*)d_in[3];
    const float* Wih0 = (const float*)d_in[4];
    const float* Whh0 = (const float*)d_in[5];
    const float* bih0 = (const float*)d_in[6];
    const float* bhh0 = (const float*)d_in[7];
    const float* Wih1 = (const float*)d_in[8];
    const float* Whh1 = (const float*)d_in[9];
    const float* bih1 = (const float*)d_in[10];
    const float* bhh1 = (const float*)d_in[11];
    const float* Wih2 = (const float*)d_in[12];
    const float* Whh2 = (const float*)d_in[13];
    const float* bih2 = (const float*)d_in[14];
    const float* bhh2 = (const float*)d_in[15];
    float* out = (float*)d_out;
    float* ws  = (float*)d_ws;

    float* table = ws;                    // 288*512
    float* hbuf  = table + VV * G4;       // 1024*256*128, reused per layer

    proj_kernel<<<VV, 512, 0, stream>>>(emb, Wih0, bih0, bhh0, table);
    lstm0_kernel<<<BB, 512, 0, stream>>>(text, table, Whh0, hbuf);
    lstm12_kernel<<<BB, 512, 0, stream>>>(Wih1, Whh1, bih1, bhh1, hbuf);
    lstm12_kernel<<<BB, 512, 0, stream>>>(Wih2, Whh2, bih2, bhh2, hbuf);
    fc_kernel<<<dim3(9, 4096), 256, 0, stream>>>(hbuf, fcW, fcb, out);
}

// Round 4
// 5805.276 us; speedup vs baseline: 4.8700x; 4.8700x over previous
//
#include <hip/hip_runtime.h>
#include <cstddef>

#define BB 256
#define SS 1024
#define VV 288
#define EE 100
#define HH 128
#define G4 512

typedef _Float16 half8 __attribute__((ext_vector_type(8)));
typedef float f32x4 __attribute__((ext_vector_type(4)));

__device__ __forceinline__ float sigmoid_f(float x) {
    return __fdividef(1.0f, 1.0f + __expf(-x));
}
__device__ __forceinline__ float tanh_f(float x) {
    x = fminf(fmaxf(x, -15.0f), 15.0f);
    float e = __expf(2.0f * x);
    return __fdividef(e - 1.0f, e + 1.0f);
}

// table[v][j] = bih0[j]+bhh0[j] + sum_e emb[v][e] * Wih0[j][e]   (fp32)
__global__ __launch_bounds__(512) void proj_kernel(
    const float* __restrict__ emb, const float* __restrict__ Wih0,
    const float* __restrict__ bih0, const float* __restrict__ bhh0,
    float* __restrict__ table)
{
    __shared__ float er[EE];
    const int v = blockIdx.x;
    const int j = threadIdx.x;
    for (int e = j; e < EE; e += 512) er[e] = emb[v * EE + e];
    __syncthreads();
    float acc = bih0[j] + bhh0[j];
    const float* wr = Wih0 + j * EE;
#pragma unroll 4
    for (int e = 0; e < EE; e++) acc = fmaf(er[e], wr[e], acc);
    table[v * G4 + j] = acc;
}

// Pack W[512][128] (fp32) into f16 MFMA B-fragments.
// Fragment (w,gt,kc): lane l, elem e  <-  B[k][n]: n(gate)=gt*128+w*16+(l&15),
// k = kc*32 + (l>>4)*8 + e.  Flat: tid = (((w*4+gt)*4+kc)*64 + l)*8 + e.
__global__ __launch_bounds__(256) void pack_kernel(
    const float* __restrict__ W, _Float16* __restrict__ out)
{
    const int tid = blockIdx.x * 256 + threadIdx.x;   // 65536 total
    const int e  = tid & 7;
    const int l  = (tid >> 3) & 63;
    const int kc = (tid >> 9) & 3;
    const int gt = (tid >> 11) & 3;
    const int w  = tid >> 13;
    const int gate = gt * 128 + w * 16 + (l & 15);
    const int k    = kc * 32 + (l >> 4) * 8 + e;
    out[tid] = (_Float16)W[gate * 128 + k];
}

// ---------------- Layer 0 (MFMA recurrence, xg from table gather) ----------
__global__ __launch_bounds__(512)
__attribute__((amdgpu_waves_per_eu(2, 2)))
void lstm0_mfma(const int* text, const float* table,
                const _Float16* Wp, _Float16* hout)
{
    __shared__ int tokL[SS * 16];          // 64 KB: tokens transposed [t][b]
    __shared__ _Float16 Hb[2][2048];       // 8 KB double-buffered h, swizzled
    const int tid = threadIdx.x;
    const int w = tid >> 6, l = tid & 63;
    const size_t B0 = (size_t)blockIdx.x * 16;
    for (int kk = 0; kk < 32; kk++) {
        const int lin = kk * 512 + tid;
        const int b = lin >> 10, t = lin & 1023;
        tokL[t * 16 + b] = text[((B0 + b) << 10) | t];
    }
    for (int i = tid; i < 2048; i += 512) Hb[0][i] = (_Float16)0.0f;
    half8 whh[4][4];
    {
        const half8* ph = (const half8*)Wp;
#pragma unroll
        for (int gt = 0; gt < 4; gt++)
#pragma unroll
            for (int kc = 0; kc < 4; kc++)
                whh[gt][kc] = ph[((w * 4 + gt) * 4 + kc) * 64 + l];
    }
    const int colD = l & 15, qd = l >> 4;
    f32x4 c_acc = {0.f, 0.f, 0.f, 0.f};
    f32x4 xg_pre[4];
    __syncthreads();
#pragma unroll
    for (int r = 0; r < 4; r++) {
        const int tk = tokL[4 * qd + r];
#pragma unroll
        for (int gt = 0; gt < 4; gt++)
            xg_pre[gt][r] = table[(size_t)tk * G4 + gt * 128 + w * 16 + colD];
    }

    auto step = [&](int T) {
        const int cur = T & 1, nxt = cur ^ 1;
        f32x4 acc[4];
#pragma unroll
        for (int gt = 0; gt < 4; gt++) acc[gt] = xg_pre[gt];
        if (T + 1 < SS) {
#pragma unroll
            for (int r = 0; r < 4; r++) {
                const int tk = tokL[(T + 1) * 16 + 4 * qd + r];
#pragma unroll
                for (int gt = 0; gt < 4; gt++)
                    xg_pre[gt][r] =
                        table[(size_t)tk * G4 + gt * 128 + w * 16 + colD];
            }
        }
#pragma unroll
        for (int kc = 0; kc < 4; kc++) {
            const int ridx =
                (colD * 128 + kc * 32 + qd * 8) ^ ((colD & 7) << 3);
            const half8 a_h = *(const half8*)&Hb[cur][ridx];
#pragma unroll
            for (int gt = 0; gt < 4; gt++)
                acc[gt] = __builtin_amdgcn_mfma_f32_16x16x32_f16(
                    a_h, whh[gt][kc], acc[gt], 0, 0, 0);
        }
#pragma unroll
        for (int r = 0; r < 4; r++) {
            const float gi = acc[0][r], gf = acc[1][r];
            const float gg = acc[2][r], go = acc[3][r];
            const float cc =
                sigmoid_f(gf) * c_acc[r] + sigmoid_f(gi) * tanh_f(gg);
            c_acc[r] = cc;
            const float hv = sigmoid_f(go) * tanh_f(cc);
            const _Float16 hh = (_Float16)hv;
            const int rr = 4 * qd + r;
            hout[((size_t)T * BB + B0 + rr) * HH + w * 16 + colD] = hh;
            Hb[nxt][(rr * 128 + w * 16 + colD) ^ ((rr & 7) << 3)] = hh;
        }
        asm volatile("s_waitcnt lgkmcnt(0)" ::: "memory");
        __builtin_amdgcn_s_barrier();
        __builtin_amdgcn_sched_barrier(0);
    };
    for (int t = 0; t < SS; t += 2) { step(t); step(t + 1); }
}

// ---------------- Layers 1,2 (MFMA recurrence, x via MFMA, K=256) ----------
__global__ __launch_bounds__(512)
__attribute__((amdgpu_waves_per_eu(2, 2)))
void lstm12_mfma(const _Float16* WpIH, const _Float16* WpHH,
                 const float* bih, const float* bhh,
                 const _Float16* xin, _Float16* hout)
{
    __shared__ _Float16 Hb[2][2048];       // 8 KB
    const int tid = threadIdx.x;
    const int w = tid >> 6, l = tid & 63;
    const size_t B0 = (size_t)blockIdx.x * 16;
    half8 whh[4][4], wih[4][4];            // 128 VGPR of weights
    {
        const half8* ph = (const half8*)WpHH;
        const half8* pi = (const half8*)WpIH;
#pragma unroll
        for (int gt = 0; gt < 4; gt++)
#pragma unroll
            for (int kc = 0; kc < 4; kc++) {
                const int fi = ((w * 4 + gt) * 4 + kc) * 64 + l;
                whh[gt][kc] = ph[fi];
                wih[gt][kc] = pi[fi];
            }
    }
    const int colD = l & 15, qd = l >> 4;
    float bias_v[4];
#pragma unroll
    for (int gt = 0; gt < 4; gt++) {
        const int g = gt * 128 + w * 16 + colD;
        bias_v[gt] = bih[g] + bhh[g];
    }
    for (int i = tid; i < 2048; i += 512) Hb[0][i] = (_Float16)0.0f;
    f32x4 c_acc = {0.f, 0.f, 0.f, 0.f};
    const _Float16* xbase = xin + (B0 + colD) * HH + qd * 8;
    half8 xA[4], xB[4];
#pragma unroll
    for (int kc = 0; kc < 4; kc++) {
        xA[kc] = *(const half8*)(xbase + (size_t)0 * BB * HH + kc * 32);
        xB[kc] = *(const half8*)(xbase + (size_t)1 * BB * HH + kc * 32);
    }
    __syncthreads();

    auto step = [&](int T, half8 (&xcur)[4]) {
        const int cur = T & 1, nxt = cur ^ 1;
        f32x4 acc[4];
#pragma unroll
        for (int gt = 0; gt < 4; gt++)
            acc[gt] = (f32x4){bias_v[gt], bias_v[gt], bias_v[gt], bias_v[gt]};
#pragma unroll
        for (int kc = 0; kc < 4; kc++)
#pragma unroll
            for (int gt = 0; gt < 4; gt++)
                acc[gt] = __builtin_amdgcn_mfma_f32_16x16x32_f16(
                    xcur[kc], wih[gt][kc], acc[gt], 0, 0, 0);
        {
            const size_t tf = (T + 2 < SS) ? (size_t)(T + 2) : (size_t)(SS - 1);
#pragma unroll
            for (int kc = 0; kc < 4; kc++)
                xcur[kc] = *(const half8*)(xbase + tf * BB * HH + kc * 32);
        }
#pragma unroll
        for (int kc = 0; kc < 4; kc++) {
            const int ridx =
                (colD * 128 + kc * 32 + qd * 8) ^ ((colD & 7) << 3);
            const half8 a_h = *(const half8*)&Hb[cur][ridx];
#pragma unroll
            for (int gt = 0; gt < 4; gt++)
                acc[gt] = __builtin_amdgcn_mfma_f32_16x16x32_f16(
                    a_h, whh[gt][kc], acc[gt], 0, 0, 0);
        }
#pragma unroll
        for (int r = 0; r < 4; r++) {
            const float gi = acc[0][r], gf = acc[1][r];
            const float gg = acc[2][r], go = acc[3][r];
            const float cc =
                sigmoid_f(gf) * c_acc[r] + sigmoid_f(gi) * tanh_f(gg);
            c_acc[r] = cc;
            const float hv = sigmoid_f(go) * tanh_f(cc);
            const _Float16 hh = (_Float16)hv;
            const int rr = 4 * qd + r;
            hout[((size_t)T * BB + B0 + rr) * HH + w * 16 + colD] = hh;
            Hb[nxt][(rr * 128 + w * 16 + colD) ^ ((rr & 7) << 3)] = hh;
        }
        asm volatile("s_waitcnt lgkmcnt(0)" ::: "memory");
        __builtin_amdgcn_s_barrier();
        __builtin_amdgcn_sched_barrier(0);
    };
    for (int t = 0; t < SS; t += 2) { step(t, xA); step(t + 1, xB); }
}

// FC head: out[m][n] = dot(h[m], fcW[n]) + fcb[n]; M=262144, N=288, K=128
__global__ __launch_bounds__(256) void fc_kernel(
    const _Float16* __restrict__ hbuf, const float* __restrict__ fcW,
    const float* __restrict__ fcb, float* __restrict__ out)
{
    __shared__ float Ash[128][68];
    __shared__ float Bsh[32][132];
    const int tid = threadIdx.x;
    const size_t mb = (size_t)blockIdx.y * 64;
    const int nb = blockIdx.x * 32;
#pragma unroll
    for (int p = 0; p < 4; p++) {
        const int fi = tid + p * 256;          // 0..1023
        const int m = fi >> 4, kc = fi & 15;
        const half8 v = *(const half8*)&hbuf[(mb + m) * HH + kc * 8];
#pragma unroll
        for (int e = 0; e < 8; e++) Ash[kc * 8 + e][m] = (float)v[e];
    }
#pragma unroll
    for (int p = 0; p < 4; p++) {
        const int fi = tid + p * 256;
        const int n = fi >> 5, k4 = fi & 31;
        ((float4*)&Bsh[n][0])[k4] =
            ((const float4*)(fcW + (size_t)(nb + n) * HH))[k4];
    }
    __syncthreads();
    const int tni = tid & 15, tmi = tid >> 4;
    const int m0 = tmi * 4, n0 = tni * 2;
    float a00=0,a01=0,a10=0,a11=0,a20=0,a21=0,a30=0,a31=0;
#pragma unroll 8
    for (int k = 0; k < 128; k++) {
        const float4 av = *((const float4*)&Ash[k][m0]);
        const float b0v = Bsh[n0][k], b1v = Bsh[n0+1][k];
        a00 = fmaf(av.x, b0v, a00); a01 = fmaf(av.x, b1v, a01);
        a10 = fmaf(av.y, b0v, a10); a11 = fmaf(av.y, b1v, a11);
        a20 = fmaf(av.z, b0v, a20); a21 = fmaf(av.z, b1v, a21);
        a30 = fmaf(av.w, b0v, a30); a31 = fmaf(av.w, b1v, a31);
    }
    const float c0 = fcb[nb + n0], c1 = fcb[nb + n0 + 1];
    float* o0 = out + (mb + m0 + 0) * VV + nb + n0;
    float* o1 = out + (mb + m0 + 1) * VV + nb + n0;
    float* o2 = out + (mb + m0 + 2) * VV + nb + n0;
    float* o3 = out + (mb + m0 + 3) * VV + nb + n0;
    *((float2*)o0) = make_float2(a00 + c0, a01 + c1);
    *((float2*)o1) = make_float2(a10 + c0, a11 + c1);
    *((float2*)o2) = make_float2(a20 + c0, a21 + c1);
    *((float2*)o3) = make_float2(a30 + c0, a31 + c1);
}

extern "C" void kernel_launch(void* const* d_in, const int* in_sizes, int n_in,
                              void* d_out, int out_size, void* d_ws, size_t ws_size,
                              hipStream_t stream)
{
    (void)in_sizes; (void)n_in; (void)out_size;
    const int*   text = (const int*)  d_in[0];
    const float* emb  = (const float*)d_in[1];
    const float* fcW  = (const float*)d_in[2];
    const float* fcb  = (const float*)d_in[3];
    const float* Wih0 = (const float*)d_in[4];
    const float* Whh0 = (const float*)d_in[5];
    const float* bih0 = (const float*)d_in[6];
    const float* bhh0 = (const float*)d_in[7];
    const float* Wih1 = (const float*)d_in[8];
    const float* Whh1 = (const float*)d_in[9];
    const float* bih1 = (const float*)d_in[10];
    const float* bhh1 = (const float*)d_in[11];
    const float* Wih2 = (const float*)d_in[12];
    const float* Whh2 = (const float*)d_in[13];
    const float* bih2 = (const float*)d_in[14];
    const float* bhh2 = (const float*)d_in[15];
    float* out = (float*)d_out;
    float* ws  = (float*)d_ws;

    float* table = ws;                               // 147456 floats
    _Float16* packs = (_Float16*)(table + VV * G4);  // 5 x 65536 halfs
    _Float16* pWhh0 = packs;
    _Float16* pWih1 = packs + 65536;
    _Float16* pWhh1 = packs + 2 * 65536;
    _Float16* pWih2 = packs + 3 * 65536;
    _Float16* pWhh2 = packs + 4 * 65536;
    _Float16* hA = packs + 5 * 65536;
    const size_t HN = (size_t)SS * BB * HH;          // 33,554,432 halfs
    const size_t need2 =
        (size_t)(VV * G4) * 4 + (5 * 65536 + 2 * HN) * sizeof(_Float16);
    _Float16* hB = (ws_size >= need2) ? (hA + HN) : hA;  // dbl-buffer if room

    proj_kernel<<<VV, 512, 0, stream>>>(emb, Wih0, bih0, bhh0, table);
    pack_kernel<<<256, 256, 0, stream>>>(Whh0, pWhh0);
    pack_kernel<<<256, 256, 0, stream>>>(Wih1, pWih1);
    pack_kernel<<<256, 256, 0, stream>>>(Whh1, pWhh1);
    pack_kernel<<<256, 256, 0, stream>>>(Wih2, pWih2);
    pack_kernel<<<256, 256, 0, stream>>>(Whh2, pWhh2);
    lstm0_mfma<<<16, 512, 0, stream>>>(text, table, pWhh0, hA);
    lstm12_mfma<<<16, 512, 0, stream>>>(pWih1, pWhh1, bih1, bhh1, hA, hB);
    lstm12_mfma<<<16, 512, 0, stream>>>(pWih2, pWhh2, bih2, bhh2, hB, hA);
    fc_kernel<<<dim3(9, 4096), 256, 0, stream>>>(hA, fcW, fcb, out);
}

// Round 5
// 2089.791 us; speedup vs baseline: 13.5285x; 2.7779x over previous
//
#include <hip/hip_runtime.h>
#include <cstddef>

#define BB 256
#define SS 1024
#define VV 288
#define EE 100
#define HH 128
#define G4 512
#define CH 16
#define NCH (SS / CH)

typedef _Float16 half8 __attribute__((ext_vector_type(8)));
typedef float f32x4 __attribute__((ext_vector_type(4)));

__device__ __forceinline__ float sigmoid_f(float x) {
    return __fdividef(1.0f, 1.0f + __expf(-x));
}
__device__ __forceinline__ float tanh_f(float x) {
    x = fminf(fmaxf(x, -15.0f), 15.0f);
    float e = __expf(2.0f * x);
    return __fdividef(e - 1.0f, e + 1.0f);
}

// table[v][j] = bih0[j]+bhh0[j] + sum_e emb[v][e] * Wih0[j][e]   (fp32)
__global__ __launch_bounds__(512) void proj_kernel(
    const float* __restrict__ emb, const float* __restrict__ Wih0,
    const float* __restrict__ bih0, const float* __restrict__ bhh0,
    float* __restrict__ table)
{
    __shared__ float er[EE];
    const int v = blockIdx.x;
    const int j = threadIdx.x;
    for (int e = j; e < EE; e += 512) er[e] = emb[v * EE + e];
    __syncthreads();
    float acc = bih0[j] + bhh0[j];
    const float* wr = Wih0 + j * EE;
#pragma unroll 4
    for (int e = 0; e < EE; e++) acc = fmaf(er[e], wr[e], acc);
    table[v * G4 + j] = acc;
}

// Pack fcW [288][128] fp32 -> f16 B-fragments: frag f=nt*4+kc, lane l, elem e
// n = nt*16+(l&15), k = kc*32+(l>>4)*8+e
__global__ __launch_bounds__(256) void pack_fc(
    const float* __restrict__ W, _Float16* __restrict__ out)
{
    const int tid = blockIdx.x * 256 + threadIdx.x;   // 36864 total
    const int e  = tid & 7;
    const int l  = (tid >> 3) & 63;
    const int f  = tid >> 9;
    const int kc = f & 3, nt = f >> 2;
    const int n = nt * 16 + (l & 15);
    const int k = kc * 32 + (l >> 4) * 8 + e;
    out[tid] = (_Float16)W[n * HH + k];
}

// ---- Fused 3-layer LSTM, wavefront-pipelined across layers ----------------
// 48 blocks: [0,16)=L0, [16,32)=L1, [32,48)=L2; block handles 16 batch rows.
// L0 writes hX; L1 reads hX, writes hY; L2 reads hY, writes hX (safe: L2's
// writes trail L1's reads of hX by >=2 chunks). Progress via agent-scope
// release/acquire atomics, one counter per (layer,tile).
__global__ __launch_bounds__(512)
__attribute__((amdgpu_waves_per_eu(2, 2)))
void lstm_pipe(const int* __restrict__ text, const float* __restrict__ table,
               const float* Whh0f,
               const float* Wih1f, const float* Whh1f,
               const float* __restrict__ bih1, const float* __restrict__ bhh1,
               const float* Wih2f, const float* Whh2f,
               const float* __restrict__ bih2, const float* __restrict__ bhh2,
               _Float16* hX, _Float16* hY, int* prog)
{
    __shared__ int tokL[SS * 16];          // 64 KB (layer-0 blocks only)
    __shared__ _Float16 Hb[2][2048];       // 8 KB double-buffered h, swizzled
    const int tid = threadIdx.x;
    const int w = tid >> 6, l = tid & 63;
    const int layer = blockIdx.x >> 4;
    const int bt = blockIdx.x & 15;
    const size_t B0 = (size_t)bt * 16;
    const int colD = l & 15, qd = l >> 4;

    const float* WhhF = (layer == 0) ? Whh0f : ((layer == 1) ? Whh1f : Whh2f);
    const float* WihF = (layer == 2) ? Wih2f : Wih1f;
    const float* bihp = (layer == 2) ? bih2 : bih1;
    const float* bhhp = (layer == 2) ? bhh2 : bhh1;
    const _Float16* xin = (layer == 1) ? hX : hY;
    _Float16* hout = (layer == 1) ? hY : hX;
    int* prog_src = prog + (layer - 1) * 16 + bt;   // only deref'd if layer>0
    int* prog_my  = prog + layer * 16 + bt;

    // Weight fragments straight from fp32 inputs (one-time, ~128 VGPR/AGPR)
    half8 whh[4][4], wih[4][4];
#pragma unroll
    for (int gt = 0; gt < 4; gt++)
#pragma unroll
        for (int kc = 0; kc < 4; kc++) {
            const int n = gt * 128 + w * 16 + colD;
            const int k0 = kc * 32 + qd * 8;
            const float4 a0 = *(const float4*)(WhhF + (size_t)n * HH + k0);
            const float4 a1 = *(const float4*)(WhhF + (size_t)n * HH + k0 + 4);
            half8 hf;
            hf[0] = (_Float16)a0.x; hf[1] = (_Float16)a0.y;
            hf[2] = (_Float16)a0.z; hf[3] = (_Float16)a0.w;
            hf[4] = (_Float16)a1.x; hf[5] = (_Float16)a1.y;
            hf[6] = (_Float16)a1.z; hf[7] = (_Float16)a1.w;
            whh[gt][kc] = hf;
            if (layer) {
                const float4 b0 = *(const float4*)(WihF + (size_t)n * HH + k0);
                const float4 b1 = *(const float4*)(WihF + (size_t)n * HH + k0 + 4);
                half8 hg;
                hg[0] = (_Float16)b0.x; hg[1] = (_Float16)b0.y;
                hg[2] = (_Float16)b0.z; hg[3] = (_Float16)b0.w;
                hg[4] = (_Float16)b1.x; hg[5] = (_Float16)b1.y;
                hg[6] = (_Float16)b1.z; hg[7] = (_Float16)b1.w;
                wih[gt][kc] = hg;
            }
        }
    float bias_v[4] = {0.f, 0.f, 0.f, 0.f};
    if (layer) {
#pragma unroll
        for (int gt = 0; gt < 4; gt++) {
            const int g = gt * 128 + w * 16 + colD;
            bias_v[gt] = bihp[g] + bhhp[g];
        }
    }
    if (layer == 0) {
        for (int kk = 0; kk < 32; kk++) {
            const int lin = kk * 512 + tid;
            const int b = lin >> 10, t = lin & 1023;
            tokL[t * 16 + b] = text[(((size_t)B0 + b) << 10) | t];
        }
    }
    for (int i = tid; i < 2048; i += 512) Hb[0][i] = (_Float16)0.0f;
    f32x4 c_acc = {0.f, 0.f, 0.f, 0.f};
    __syncthreads();

    auto wait_src = [&](int target) {
        int v = __hip_atomic_load(prog_src, __ATOMIC_RELAXED,
                                  __HIP_MEMORY_SCOPE_AGENT);
        while (v < target) {
            __builtin_amdgcn_s_sleep(8);
            v = __hip_atomic_load(prog_src, __ATOMIC_RELAXED,
                                  __HIP_MEMORY_SCOPE_AGENT);
        }
        v = __hip_atomic_load(prog_src, __ATOMIC_ACQUIRE,
                              __HIP_MEMORY_SCOPE_AGENT);
        asm volatile("" :: "v"(v));
    };
    auto signal = [&](int c) {
        asm volatile("s_waitcnt vmcnt(0)" ::: "memory");
        __builtin_amdgcn_s_barrier();
        if (tid == 0) {
            __threadfence();
            __hip_atomic_store(prog_my, (c + 1) * CH, __ATOMIC_RELEASE,
                               __HIP_MEMORY_SCOPE_AGENT);
        }
    };
    auto elem_store = [&](f32x4* acc, int T) {
#pragma unroll
        for (int r = 0; r < 4; r++) {
            const float gi = acc[0][r], gf = acc[1][r];
            const float gg = acc[2][r], go = acc[3][r];
            const float cc =
                sigmoid_f(gf) * c_acc[r] + sigmoid_f(gi) * tanh_f(gg);
            c_acc[r] = cc;
            const float hv = sigmoid_f(go) * tanh_f(cc);
            const _Float16 hh = (_Float16)hv;
            const int rr = 4 * qd + r;
            hout[((size_t)T * BB + B0 + rr) * HH + w * 16 + colD] = hh;
            Hb[(T & 1) ^ 1][(rr * 128 + w * 16 + colD) ^ ((rr & 7) << 3)] = hh;
        }
        asm volatile("s_waitcnt lgkmcnt(0)" ::: "memory");
        __builtin_amdgcn_s_barrier();
        __builtin_amdgcn_sched_barrier(0);
    };

    if (layer == 0) {
        f32x4 xg_pre[4];
#pragma unroll
        for (int r = 0; r < 4; r++) {
            const int tk = tokL[4 * qd + r];
#pragma unroll
            for (int gt = 0; gt < 4; gt++)
                xg_pre[gt][r] =
                    table[(size_t)tk * G4 + gt * 128 + w * 16 + colD];
        }
        for (int c = 0; c < NCH; c++) {
            for (int tt = 0; tt < CH; tt++) {
                const int T = c * CH + tt;
                const int cur = T & 1;
                f32x4 acc[4];
#pragma unroll
                for (int gt = 0; gt < 4; gt++) acc[gt] = xg_pre[gt];
                if (T + 1 < SS) {
#pragma unroll
                    for (int r = 0; r < 4; r++) {
                        const int tk = tokL[(T + 1) * 16 + 4 * qd + r];
#pragma unroll
                        for (int gt = 0; gt < 4; gt++)
                            xg_pre[gt][r] = table[(size_t)tk * G4 + gt * 128 +
                                                  w * 16 + colD];
                    }
                }
#pragma unroll
                for (int kc = 0; kc < 4; kc++) {
                    const int ridx =
                        (colD * 128 + kc * 32 + qd * 8) ^ ((colD & 7) << 3);
                    const half8 a_h = *(const half8*)&Hb[cur][ridx];
#pragma unroll
                    for (int gt = 0; gt < 4; gt++)
                        acc[gt] = __builtin_amdgcn_mfma_f32_16x16x32_f16(
                            a_h, whh[gt][kc], acc[gt], 0, 0, 0);
                }
                elem_store(acc, T);
            }
            signal(c);
        }
    } else {
        wait_src(2 * CH);
        const _Float16* xbase = xin + (B0 + colD) * HH + qd * 8;
        half8 xA[4], xB[4];
#pragma unroll
        for (int kc = 0; kc < 4; kc++) {
            xA[kc] = *(const half8*)(xbase + (size_t)0 * BB * HH + kc * 32);
            xB[kc] = *(const half8*)(xbase + (size_t)1 * BB * HH + kc * 32);
        }
        auto step = [&](int T, half8(&xcur)[4]) {
            const int cur = T & 1;
            f32x4 acc[4];
#pragma unroll
            for (int gt = 0; gt < 4; gt++)
                acc[gt] = (f32x4){bias_v[gt], bias_v[gt], bias_v[gt],
                                  bias_v[gt]};
#pragma unroll
            for (int kc = 0; kc < 4; kc++)
#pragma unroll
                for (int gt = 0; gt < 4; gt++)
                    acc[gt] = __builtin_amdgcn_mfma_f32_16x16x32_f16(
                        xcur[kc], wih[gt][kc], acc[gt], 0, 0, 0);
            {
                const size_t tf =
                    (T + 2 < SS) ? (size_t)(T + 2) : (size_t)(SS - 1);
#pragma unroll
                for (int kc = 0; kc < 4; kc++)
                    xcur[kc] =
                        *(const half8*)(xbase + tf * BB * HH + kc * 32);
            }
#pragma unroll
            for (int kc = 0; kc < 4; kc++) {
                const int ridx =
                    (colD * 128 + kc * 32 + qd * 8) ^ ((colD & 7) << 3);
                const half8 a_h = *(const half8*)&Hb[cur][ridx];
#pragma unroll
                for (int gt = 0; gt < 4; gt++)
                    acc[gt] = __builtin_amdgcn_mfma_f32_16x16x32_f16(
                        a_h, whh[gt][kc], acc[gt], 0, 0, 0);
            }
            elem_store(acc, T);
        };
        for (int c = 0; c < NCH; c++) {
            if (c) {
                const int tgt = (c + 2) * CH;
                wait_src(tgt > SS ? SS : tgt);
            }
            for (int tt = 0; tt < CH; tt += 2) {
                step(c * CH + tt, xA);
                step(c * CH + tt + 1, xB);
            }
            if (layer == 1) signal(c);
        }
    }
}

// ---- FC head via MFMA: out[m][n] = h2[m]·fcW[n] + fcb[n] ------------------
// M=262144, N=288 (18 n-tiles), K=128. Block: 4 waves x 16 rows = 64 rows.
__global__ __launch_bounds__(256) void fc_mfma(
    const _Float16* __restrict__ h2, const _Float16* __restrict__ pfcW,
    const float* __restrict__ fcb, float* __restrict__ out)
{
    const int tid = threadIdx.x, wv = tid >> 6, l = tid & 63;
    const int colD = l & 15, qd = l >> 4;
    const size_t m0 = (size_t)blockIdx.x * 64 + wv * 16;
    half8 a[4];
#pragma unroll
    for (int kc = 0; kc < 4; kc++)
        a[kc] = *(const half8*)(h2 + (m0 + colD) * HH + kc * 32 + qd * 8);
    float fcb_r[18];
#pragma unroll
    for (int nt = 0; nt < 18; nt++) fcb_r[nt] = fcb[nt * 16 + colD];
#pragma unroll
    for (int nt = 0; nt < 18; nt++) {
        f32x4 acc = {0.f, 0.f, 0.f, 0.f};
#pragma unroll
        for (int kc = 0; kc < 4; kc++) {
            const half8 b = *(const half8*)(pfcW + (((nt * 4 + kc) << 6) + l) * 8);
            acc = __builtin_amdgcn_mfma_f32_16x16x32_f16(a[kc], b, acc, 0, 0, 0);
        }
#pragma unroll
        for (int r = 0; r < 4; r++)
            out[(m0 + 4 * qd + r) * VV + nt * 16 + colD] = acc[r] + fcb_r[nt];
    }
}

extern "C" void kernel_launch(void* const* d_in, const int* in_sizes, int n_in,
                              void* d_out, int out_size, void* d_ws, size_t ws_size,
                              hipStream_t stream)
{
    (void)in_sizes; (void)n_in; (void)ws_size;
    const int*   text = (const int*)  d_in[0];
    const float* emb  = (const float*)d_in[1];
    const float* fcW  = (const float*)d_in[2];
    const float* fcb  = (const float*)d_in[3];
    const float* Wih0 = (const float*)d_in[4];
    const float* Whh0 = (const float*)d_in[5];
    const float* bih0 = (const float*)d_in[6];
    const float* bhh0 = (const float*)d_in[7];
    const float* Wih1 = (const float*)d_in[8];
    const float* Whh1 = (const float*)d_in[9];
    const float* bih1 = (const float*)d_in[10];
    const float* bhh1 = (const float*)d_in[11];
    const float* Wih2 = (const float*)d_in[12];
    const float* Whh2 = (const float*)d_in[13];
    const float* bih2 = (const float*)d_in[14];
    const float* bhh2 = (const float*)d_in[15];
    float* out = (float*)d_out;

    // ws layout (fits the proven-available 134,807,552 B exactly):
    //   [0, 589824)                      fp32 table; reused as pfcW after pipe
    //   [589824, +64MB)                  hX (h0 and h2, f16)
    //   [589824+64MB, +64MB)             hY (h1, f16)
    float* table = (float*)d_ws;
    _Float16* hX = (_Float16*)((char*)d_ws + 589824);
    _Float16* hY = hX + (size_t)SS * BB * HH;
    _Float16* pfcW = (_Float16*)d_ws;
    int* prog = ((int*)d_out) + ((size_t)out_size - 64);  // tail of out

    hipMemsetAsync(prog, 0, 64 * sizeof(int), stream);
    proj_kernel<<<VV, 512, 0, stream>>>(emb, Wih0, bih0, bhh0, table);
    lstm_pipe<<<48, 512, 0, stream>>>(text, table, Whh0,
                                      Wih1, Whh1, bih1, bhh1,
                                      Wih2, Whh2, bih2, bhh2,
                                      hX, hY, prog);
    pack_fc<<<144, 256, 0, stream>>>(fcW, pfcW);
    fc_mfma<<<4096, 256, 0, stream>>>(hX, pfcW, fcb, out);
}

// Round 6
// 1727.200 us; speedup vs baseline: 16.3685x; 1.2099x over previous
//
#include <hip/hip_runtime.h>
#include <cstddef>
#include <cstdint>

#define BB 256
#define SS 1024
#define VV 288
#define EE 100
#define HH 128
#define G4 512
#define CH 16
#define NCH (SS / CH)

typedef _Float16 half8 __attribute__((ext_vector_type(8)));
typedef float f32x4 __attribute__((ext_vector_type(4)));

// clamp-free, NaN-free fast activations (v_exp_f32 is exp2; v_rcp_f32)
__device__ __forceinline__ float sig_f(float x) {
    return __builtin_amdgcn_rcpf(1.0f +
           __builtin_amdgcn_exp2f(-1.4426950408889634f * x));
}
__device__ __forceinline__ float tanh2_f(float x) {
    return 2.0f * __builtin_amdgcn_rcpf(1.0f +
           __builtin_amdgcn_exp2f(-2.8853900817779268f * x)) - 1.0f;
}

// table[v][j] = bih0[j]+bhh0[j] + sum_e emb[v][e] * Wih0[j][e]   (fp32)
__global__ __launch_bounds__(512) void proj_kernel(
    const float* __restrict__ emb, const float* __restrict__ Wih0,
    const float* __restrict__ bih0, const float* __restrict__ bhh0,
    float* __restrict__ table)
{
    __shared__ float er[EE];
    const int v = blockIdx.x;
    const int j = threadIdx.x;
    for (int e = j; e < EE; e += 512) er[e] = emb[v * EE + e];
    __syncthreads();
    float acc = bih0[j] + bhh0[j];
    const float* wr = Wih0 + j * EE;
#pragma unroll 4
    for (int e = 0; e < EE; e++) acc = fmaf(er[e], wr[e], acc);
    table[v * G4 + j] = acc;
}

// Pack fcW [288][128] fp32 -> f16 B-fragments: frag f=nt*4+kc, lane l, elem e
__global__ __launch_bounds__(256) void pack_fc(
    const float* __restrict__ W, _Float16* __restrict__ out)
{
    const int tid = blockIdx.x * 256 + threadIdx.x;   // 36864 total
    const int e  = tid & 7;
    const int l  = (tid >> 3) & 63;
    const int f  = tid >> 9;
    const int kc = f & 3, nt = f >> 2;
    const int n = nt * 16 + (l & 15);
    const int k = kc * 32 + (l >> 4) * 8 + e;
    out[tid] = (_Float16)W[n * HH + k];
}

// ---- Fused 3-layer LSTM, wavefront-pipelined across layers ----------------
__global__ __launch_bounds__(512)
__attribute__((amdgpu_waves_per_eu(2, 2)))
void lstm_pipe(const int* __restrict__ text, const float* __restrict__ table,
               const float* Whh0f,
               const float* Wih1f, const float* Whh1f,
               const float* __restrict__ bih1, const float* __restrict__ bhh1,
               const float* Wih2f, const float* Whh2f,
               const float* __restrict__ bih2, const float* __restrict__ bhh2,
               _Float16* hX, _Float16* hY, int* prog)
{
    __shared__ int tokL[SS * 16];          // 64 KB (layer-0 blocks only)
    __shared__ _Float16 Hb[2][2048];       // 8 KB double-buffered h, swizzled
    const int tid = threadIdx.x;
    const int w = tid >> 6, l = tid & 63;
    const int layer = blockIdx.x >> 4;
    const int bt = blockIdx.x & 15;
    const int B0 = bt * 16;
    const int colD = l & 15, qd = l >> 4;
    const int gcol = w * 16 + colD;

    const float* WhhF = (layer == 0) ? Whh0f : ((layer == 1) ? Whh1f : Whh2f);
    const float* WihF = (layer == 2) ? Wih2f : Wih1f;
    const float* bihp = (layer == 2) ? bih2 : bih1;
    const float* bhhp = (layer == 2) ? bhh2 : bhh1;
    const _Float16* xin = (layer == 1) ? hX : hY;
    _Float16* hout = (layer == 1) ? hY : hX;
    int* prog_src = prog + (layer - 1) * 16 + bt;
    int* prog_my  = prog + layer * 16 + bt;

    // Weight fragments straight from fp32 inputs (one-time)
    half8 whh[4][4], wih[4][4];
#pragma unroll
    for (int gt = 0; gt < 4; gt++)
#pragma unroll
        for (int kc = 0; kc < 4; kc++) {
            const int n = gt * 128 + gcol;
            const int k0 = kc * 32 + qd * 8;
            const float4 a0 = *(const float4*)(WhhF + (size_t)n * HH + k0);
            const float4 a1 = *(const float4*)(WhhF + (size_t)n * HH + k0 + 4);
            half8 hf;
            hf[0] = (_Float16)a0.x; hf[1] = (_Float16)a0.y;
            hf[2] = (_Float16)a0.z; hf[3] = (_Float16)a0.w;
            hf[4] = (_Float16)a1.x; hf[5] = (_Float16)a1.y;
            hf[6] = (_Float16)a1.z; hf[7] = (_Float16)a1.w;
            whh[gt][kc] = hf;
            if (layer) {
                const float4 b0 = *(const float4*)(WihF + (size_t)n * HH + k0);
                const float4 b1 = *(const float4*)(WihF + (size_t)n * HH + k0 + 4);
                half8 hg;
                hg[0] = (_Float16)b0.x; hg[1] = (_Float16)b0.y;
                hg[2] = (_Float16)b0.z; hg[3] = (_Float16)b0.w;
                hg[4] = (_Float16)b1.x; hg[5] = (_Float16)b1.y;
                hg[6] = (_Float16)b1.z; hg[7] = (_Float16)b1.w;
                wih[gt][kc] = hg;
            }
        }
    f32x4 bias_frag[4];
#pragma unroll
    for (int gt = 0; gt < 4; gt++) {
        float b = 0.0f;
        if (layer) {
            const int g = gt * 128 + gcol;
            b = bihp[g] + bhhp[g];
        }
        bias_frag[gt] = (f32x4){b, b, b, b};
    }
    if (layer == 0) {
        for (int kk = 0; kk < 32; kk++) {
            const int lin = kk * 512 + tid;
            const int b = lin >> 10, t = lin & 1023;
            tokL[t * 16 + b] = text[(((size_t)B0 + b) << 10) | t];
        }
    }
    for (int i = tid; i < 2048; i += 512) Hb[0][i] = (_Float16)0.0f;
    f32x4 c_acc = {0.f, 0.f, 0.f, 0.f};

    // loop-invariant LDS element indices (A-fragment reads, h writes)
    int rd_idx[4], wr_idx[4];
#pragma unroll
    for (int kc = 0; kc < 4; kc++)
        rd_idx[kc] = (colD * 128 + kc * 32 + qd * 8) ^ ((colD & 7) << 3);
#pragma unroll
    for (int r = 0; r < 4; r++) {
        const int rr = 4 * qd + r;
        wr_idx[r] = (rr * 128 + gcol) ^ ((rr & 7) << 3);
    }
    __syncthreads();

    auto wait_src = [&](int target) {
        int v = __hip_atomic_load(prog_src, __ATOMIC_RELAXED,
                                  __HIP_MEMORY_SCOPE_AGENT);
        while (v < target) {
            __builtin_amdgcn_s_sleep(8);
            v = __hip_atomic_load(prog_src, __ATOMIC_RELAXED,
                                  __HIP_MEMORY_SCOPE_AGENT);
        }
        v = __hip_atomic_load(prog_src, __ATOMIC_ACQUIRE,
                              __HIP_MEMORY_SCOPE_AGENT);
        asm volatile("" :: "v"(v));
    };
    auto signal = [&](int c) {
        asm volatile("s_waitcnt vmcnt(0)" ::: "memory");
        __builtin_amdgcn_s_barrier();
        if (tid == 0) {
            __threadfence();
            __hip_atomic_store(prog_my, (c + 1) * CH, __ATOMIC_RELEASE,
                               __HIP_MEMORY_SCOPE_AGENT);
        }
    };
    auto finish = [&](f32x4 (&acc)[4], int T, int nxt) {
#pragma unroll
        for (int r = 0; r < 4; r++) {
            const float si = sig_f(acc[0][r]);
            const float sf = sig_f(acc[1][r]);
            const float tg = tanh2_f(acc[2][r]);
            const float so = sig_f(acc[3][r]);
            const float cc = fmaf(sf, c_acc[r], si * tg);
            c_acc[r] = cc;
            const float hv = so * tanh2_f(cc);
            const _Float16 hh = (_Float16)hv;
            Hb[nxt][wr_idx[r]] = hh;
            hout[(uint32_t)(T * BB + B0 + 4 * qd + r) * HH + gcol] = hh;
        }
        asm volatile("s_waitcnt lgkmcnt(0)" ::: "memory");
        __builtin_amdgcn_s_barrier();
    };

    if (layer == 0) {
        f32x4 xgA[4], xgB[4];
        {   // gather xg for T=0
            const int4 tk0 = *(const int4*)&tokL[4 * qd];
            const float* g0 = table + (size_t)tk0.x * G4 + gcol;
            const float* g1 = table + (size_t)tk0.y * G4 + gcol;
            const float* g2 = table + (size_t)tk0.z * G4 + gcol;
            const float* g3 = table + (size_t)tk0.w * G4 + gcol;
#pragma unroll
            for (int gt = 0; gt < 4; gt++) {
                xgA[gt][0] = g0[gt * 128];
                xgA[gt][1] = g1[gt * 128];
                xgA[gt][2] = g2[gt * 128];
                xgA[gt][3] = g3[gt * 128];
            }
        }
        auto step0 = [&](int T, int cur, f32x4 (&xgc)[4], f32x4 (&xgn)[4]) {
            half8 a_h[4];
#pragma unroll
            for (int kc = 0; kc < 4; kc++)
                a_h[kc] = *(const half8*)&Hb[cur][rd_idx[kc]];
            const int Tn = (T + 1 < SS) ? T + 1 : T;
            const int4 tkn = *(const int4*)&tokL[Tn * 16 + 4 * qd];
            f32x4 acc[4];
#pragma unroll
            for (int gt = 0; gt < 4; gt++) {
                acc[gt] = __builtin_amdgcn_mfma_f32_16x16x32_f16(
                    a_h[0], whh[gt][0], xgc[gt], 0, 0, 0);
#pragma unroll
                for (int kc = 1; kc < 4; kc++)
                    acc[gt] = __builtin_amdgcn_mfma_f32_16x16x32_f16(
                        a_h[kc], whh[gt][kc], acc[gt], 0, 0, 0);
            }
            {   // gather xg for T+1 (lgkm wait overlaps MFMA execution)
                const float* g0 = table + (size_t)tkn.x * G4 + gcol;
                const float* g1 = table + (size_t)tkn.y * G4 + gcol;
                const float* g2 = table + (size_t)tkn.z * G4 + gcol;
                const float* g3 = table + (size_t)tkn.w * G4 + gcol;
#pragma unroll
                for (int gt = 0; gt < 4; gt++) {
                    xgn[gt][0] = g0[gt * 128];
                    xgn[gt][1] = g1[gt * 128];
                    xgn[gt][2] = g2[gt * 128];
                    xgn[gt][3] = g3[gt * 128];
                }
            }
            finish(acc, T, cur ^ 1);
        };
        for (int c = 0; c < NCH; c++) {
            for (int tt = 0; tt < CH; tt += 2) {
                step0(c * CH + tt,     0, xgA, xgB);
                step0(c * CH + tt + 1, 1, xgB, xgA);
            }
            signal(c);
        }
    } else {
        wait_src(2 * CH);
        const _Float16* xbase = xin + ((size_t)B0 + colD) * HH + qd * 8;
        half8 xA[4], xB[4];
#pragma unroll
        for (int kc = 0; kc < 4; kc++) {
            xA[kc] = *(const half8*)(xbase + (size_t)0 * BB * HH + kc * 32);
            xB[kc] = *(const half8*)(xbase + (size_t)1 * BB * HH + kc * 32);
        }
        auto stepK = [&](int T, int cur, half8 (&xcur)[4]) {
            half8 a_h[4];
#pragma unroll
            for (int kc = 0; kc < 4; kc++)
                a_h[kc] = *(const half8*)&Hb[cur][rd_idx[kc]];
            f32x4 acc[4];
#pragma unroll
            for (int gt = 0; gt < 4; gt++) {
                acc[gt] = __builtin_amdgcn_mfma_f32_16x16x32_f16(
                    xcur[0], wih[gt][0], bias_frag[gt], 0, 0, 0);
#pragma unroll
                for (int kc = 1; kc < 4; kc++)
                    acc[gt] = __builtin_amdgcn_mfma_f32_16x16x32_f16(
                        xcur[kc], wih[gt][kc], acc[gt], 0, 0, 0);
            }
            {   // prefetch x for T+2 (stays in flight across barriers)
                const size_t tf =
                    (T + 2 < SS) ? (size_t)(T + 2) : (size_t)(SS - 1);
#pragma unroll
                for (int kc = 0; kc < 4; kc++)
                    xcur[kc] = *(const half8*)(xbase + tf * BB * HH + kc * 32);
            }
#pragma unroll
            for (int kc = 0; kc < 4; kc++)
#pragma unroll
                for (int gt = 0; gt < 4; gt++)
                    acc[gt] = __builtin_amdgcn_mfma_f32_16x16x32_f16(
                        a_h[kc], whh[gt][kc], acc[gt], 0, 0, 0);
            finish(acc, T, cur ^ 1);
        };
        for (int c = 0; c < NCH; c++) {
            if (c) {
                const int tgt = (c + 2) * CH;
                wait_src(tgt > SS ? SS : tgt);
            }
            for (int tt = 0; tt < CH; tt += 2) {
                stepK(c * CH + tt,     0, xA);
                stepK(c * CH + tt + 1, 1, xB);
            }
            if (layer == 1) signal(c);
        }
    }
}

// ---- FC head via MFMA: out[m][n] = h2[m]·fcW[n] + fcb[n] ------------------
__global__ __launch_bounds__(256) void fc_mfma(
    const _Float16* __restrict__ h2, const _Float16* __restrict__ pfcW,
    const float* __restrict__ fcb, float* __restrict__ out)
{
    const int tid = threadIdx.x, wv = tid >> 6, l = tid & 63;
    const int colD = l & 15, qd = l >> 4;
    const size_t m0 = (size_t)blockIdx.x * 64 + wv * 16;
    half8 a[4];
#pragma unroll
    for (int kc = 0; kc < 4; kc++)
        a[kc] = *(const half8*)(h2 + (m0 + colD) * HH + kc * 32 + qd * 8);
    float fcb_r[18];
#pragma unroll
    for (int nt = 0; nt < 18; nt++) fcb_r[nt] = fcb[nt * 16 + colD];
#pragma unroll
    for (int nt = 0; nt < 18; nt++) {
        f32x4 acc = {0.f, 0.f, 0.f, 0.f};
#pragma unroll
        for (int kc = 0; kc < 4; kc++) {
            const half8 b = *(const half8*)(pfcW + (((nt * 4 + kc) << 6) + l) * 8);
            acc = __builtin_amdgcn_mfma_f32_16x16x32_f16(a[kc], b, acc, 0, 0, 0);
        }
#pragma unroll
        for (int r = 0; r < 4; r++)
            out[(m0 + 4 * qd + r) * VV + nt * 16 + colD] = acc[r] + fcb_r[nt];
    }
}

extern "C" void kernel_launch(void* const* d_in, const int* in_sizes, int n_in,
                              void* d_out, int out_size, void* d_ws, size_t ws_size,
                              hipStream_t stream)
{
    (void)in_sizes; (void)n_in; (void)ws_size;
    const int*   text = (const int*)  d_in[0];
    const float* emb  = (const float*)d_in[1];
    const float* fcW  = (const float*)d_in[2];
    const float* fcb  = (const float*)d_in[3];
    const float* Wih0 = (const float*)d_in[4];
    const float* Whh0 = (const float*)d_in[5];
    const float* bih0 = (const float*)d_in[6];
    const float* bhh0 = (const float*)d_in[7];
    const float* Wih1 = (const float*)d_in[8];
    const float* Whh1 = (const float*)d_in[9];
    const float* bih1 = (const float*)d_in[10];
    const float* bhh1 = (const float*)d_in[11];
    const float* Wih2 = (const float*)d_in[12];
    const float* Whh2 = (const float*)d_in[13];
    const float* bih2 = (const float*)d_in[14];
    const float* bhh2 = (const float*)d_in[15];
    float* out = (float*)d_out;

    float* table = (float*)d_ws;
    _Float16* hX = (_Float16*)((char*)d_ws + 589824);
    _Float16* hY = hX + (size_t)SS * BB * HH;
    _Float16* pfcW = (_Float16*)d_ws;
    int* prog = ((int*)d_out) + ((size_t)out_size - 64);  // tail of out

    hipMemsetAsync(prog, 0, 64 * sizeof(int), stream);
    proj_kernel<<<VV, 512, 0, stream>>>(emb, Wih0, bih0, bhh0, table);
    lstm_pipe<<<48, 512, 0, stream>>>(text, table, Whh0,
                                      Wih1, Whh1, bih1, bhh1,
                                      Wih2, Whh2, bih2, bhh2,
                                      hX, hY, prog);
    pack_fc<<<144, 256, 0, stream>>>(fcW, pfcW);
    fc_mfma<<<4096, 256, 0, stream>>>(hX, pfcW, fcb, out);
}

// Round 7
// 1603.141 us; speedup vs baseline: 17.6352x; 1.0774x over previous
//
#include <hip/hip_runtime.h>
#include <cstddef>
#include <cstdint>

#define BB 256
#define SS 1024
#define VV 288
#define EE 100
#define HH 128
#define G4 512
#define CH 16
#define NCH (SS / CH)

typedef _Float16 half8 __attribute__((ext_vector_type(8)));
typedef float f32x4 __attribute__((ext_vector_type(4)));

// clamp-free, NaN-free fast activations (v_exp_f32 is exp2; v_rcp_f32)
__device__ __forceinline__ float sig_f(float x) {
    return __builtin_amdgcn_rcpf(1.0f +
           __builtin_amdgcn_exp2f(-1.4426950408889634f * x));
}
__device__ __forceinline__ float tanh2_f(float x) {
    return 2.0f * __builtin_amdgcn_rcpf(1.0f +
           __builtin_amdgcn_exp2f(-2.8853900817779268f * x)) - 1.0f;
}

// table[v][j] = bih0[j]+bhh0[j] + sum_e emb[v][e] * Wih0[j][e]   (fp32)
__global__ __launch_bounds__(512) void proj_kernel(
    const float* __restrict__ emb, const float* __restrict__ Wih0,
    const float* __restrict__ bih0, const float* __restrict__ bhh0,
    float* __restrict__ table)
{
    __shared__ float er[EE];
    const int v = blockIdx.x;
    const int j = threadIdx.x;
    for (int e = j; e < EE; e += 512) er[e] = emb[v * EE + e];
    __syncthreads();
    float acc = bih0[j] + bhh0[j];
    const float* wr = Wih0 + j * EE;
#pragma unroll 4
    for (int e = 0; e < EE; e++) acc = fmaf(er[e], wr[e], acc);
    table[v * G4 + j] = acc;
}

// Pack fcW [288][128] fp32 -> f16 B-fragments: frag f=nt*4+kc, lane l, elem e
__global__ __launch_bounds__(256) void pack_fc(
    const float* __restrict__ W, _Float16* __restrict__ out)
{
    const int tid = blockIdx.x * 256 + threadIdx.x;   // 36864 total
    const int e  = tid & 7;
    const int l  = (tid >> 3) & 63;
    const int f  = tid >> 9;
    const int kc = f & 3, nt = f >> 2;
    const int n = nt * 16 + (l & 15);
    const int k = kc * 32 + (l >> 4) * 8 + e;
    out[tid] = (_Float16)W[n * HH + k];
}

// ---- Fused 3-layer LSTM, wavefront-pipelined across layers ----------------
__global__ __launch_bounds__(512)
__attribute__((amdgpu_waves_per_eu(2, 2)))
void lstm_pipe(const int* __restrict__ text, const float* __restrict__ table,
               const float* Whh0f,
               const float* Wih1f, const float* Whh1f,
               const float* __restrict__ bih1, const float* __restrict__ bhh1,
               const float* Wih2f, const float* Whh2f,
               const float* __restrict__ bih2, const float* __restrict__ bhh2,
               _Float16* hX, _Float16* hY, int* prog)
{
    __shared__ int tokL[SS * 16];          // 64 KB (layer-0 blocks only)
    __shared__ _Float16 Hb[2][2048];       // 8 KB double-buffered h, swizzled
    const int tid = threadIdx.x;
    const int w = tid >> 6, l = tid & 63;
    const int layer = blockIdx.x >> 4;
    const int bt = blockIdx.x & 15;
    const int B0 = bt * 16;
    const int colD = l & 15, qd = l >> 4;
    const int gcol = w * 16 + colD;

    const float* WhhF = (layer == 0) ? Whh0f : ((layer == 1) ? Whh1f : Whh2f);
    const float* WihF = (layer == 2) ? Wih2f : Wih1f;
    const float* bihp = (layer == 2) ? bih2 : bih1;
    const float* bhhp = (layer == 2) ? bhh2 : bhh1;
    const _Float16* xin = (layer == 1) ? hX : hY;
    _Float16* hout = (layer == 1) ? hY : hX;
    int* prog_src = prog + (layer - 1) * 16 + bt;
    int* prog_my  = prog + layer * 16 + bt;

    // Weight fragments straight from fp32 inputs (one-time)
    half8 whh[4][4], wih[4][4];
#pragma unroll
    for (int gt = 0; gt < 4; gt++)
#pragma unroll
        for (int kc = 0; kc < 4; kc++) {
            const int n = gt * 128 + gcol;
            const int k0 = kc * 32 + qd * 8;
            const float4 a0 = *(const float4*)(WhhF + (size_t)n * HH + k0);
            const float4 a1 = *(const float4*)(WhhF + (size_t)n * HH + k0 + 4);
            half8 hf;
            hf[0] = (_Float16)a0.x; hf[1] = (_Float16)a0.y;
            hf[2] = (_Float16)a0.z; hf[3] = (_Float16)a0.w;
            hf[4] = (_Float16)a1.x; hf[5] = (_Float16)a1.y;
            hf[6] = (_Float16)a1.z; hf[7] = (_Float16)a1.w;
            whh[gt][kc] = hf;
            if (layer) {
                const float4 b0 = *(const float4*)(WihF + (size_t)n * HH + k0);
                const float4 b1 = *(const float4*)(WihF + (size_t)n * HH + k0 + 4);
                half8 hg;
                hg[0] = (_Float16)b0.x; hg[1] = (_Float16)b0.y;
                hg[2] = (_Float16)b0.z; hg[3] = (_Float16)b0.w;
                hg[4] = (_Float16)b1.x; hg[5] = (_Float16)b1.y;
                hg[6] = (_Float16)b1.z; hg[7] = (_Float16)b1.w;
                wih[gt][kc] = hg;
            }
        }
    f32x4 bias_frag[4];
#pragma unroll
    for (int gt = 0; gt < 4; gt++) {
        float b = 0.0f;
        if (layer) {
            const int g = gt * 128 + gcol;
            b = bihp[g] + bhhp[g];
        }
        bias_frag[gt] = (f32x4){b, b, b, b};
    }
    if (layer == 0) {
        for (int kk = 0; kk < 32; kk++) {
            const int lin = kk * 512 + tid;
            const int b = lin >> 10, t = lin & 1023;
            tokL[t * 16 + b] = text[(((size_t)B0 + b) << 10) | t];
        }
    }
    for (int i = tid; i < 2048; i += 512) Hb[0][i] = (_Float16)0.0f;
    f32x4 c_acc = {0.f, 0.f, 0.f, 0.f};

    // loop-invariant LDS element indices (A-fragment reads, h writes)
    int rd_idx[4], wr_idx[4];
#pragma unroll
    for (int kc = 0; kc < 4; kc++)
        rd_idx[kc] = (colD * 128 + kc * 32 + qd * 8) ^ ((colD & 7) << 3);
#pragma unroll
    for (int r = 0; r < 4; r++) {
        const int rr = 4 * qd + r;
        wr_idx[r] = (rr * 128 + gcol) ^ ((rr & 7) << 3);
    }
    // bumped output pointer (row r at houtp[r*HH])
    _Float16* houtp = hout + ((size_t)B0 + 4 * qd) * HH + gcol;
    __syncthreads();

    auto wait_src = [&](int target) {
        int v = __hip_atomic_load(prog_src, __ATOMIC_RELAXED,
                                  __HIP_MEMORY_SCOPE_AGENT);
        while (v < target) {
            __builtin_amdgcn_s_sleep(8);
            v = __hip_atomic_load(prog_src, __ATOMIC_RELAXED,
                                  __HIP_MEMORY_SCOPE_AGENT);
        }
        v = __hip_atomic_load(prog_src, __ATOMIC_ACQUIRE,
                              __HIP_MEMORY_SCOPE_AGENT);
        asm volatile("" :: "v"(v));
    };
    auto signal = [&](int c) {
        asm volatile("s_waitcnt vmcnt(0)" ::: "memory");
        __builtin_amdgcn_s_barrier();
        if (tid == 0) {
            __threadfence();
            __hip_atomic_store(prog_my, (c + 1) * CH, __ATOMIC_RELEASE,
                               __HIP_MEMORY_SCOPE_AGENT);
        }
    };
    // finish: p,q are the two partial h-chain accumulators; acc = p+q
    auto finish = [&](f32x4 (&p)[4], f32x4 (&q)[4], int nxt) {
#pragma unroll
        for (int r = 0; r < 4; r++) {
            const float gi = p[0][r] + q[0][r];
            const float gf = p[1][r] + q[1][r];
            const float gg = p[2][r] + q[2][r];
            const float go = p[3][r] + q[3][r];
            const float si = sig_f(gi);
            const float sf = sig_f(gf);
            const float tg = tanh2_f(gg);
            const float so = sig_f(go);
            const float cc = fmaf(sf, c_acc[r], si * tg);
            c_acc[r] = cc;
            const float hv = so * tanh2_f(cc);
            const _Float16 hh = (_Float16)hv;
            Hb[nxt][wr_idx[r]] = hh;
            houtp[r * HH] = hh;
        }
        houtp += BB * HH;
        asm volatile("s_waitcnt lgkmcnt(0)" ::: "memory");
        __builtin_amdgcn_s_barrier();
    };

    if (layer == 0) {
        f32x4 xgA[4], xgB[4];
        {   // gather xg for T=0
            const int4 tk0 = *(const int4*)&tokL[4 * qd];
            const float* g0 = table + (size_t)tk0.x * G4 + gcol;
            const float* g1 = table + (size_t)tk0.y * G4 + gcol;
            const float* g2 = table + (size_t)tk0.z * G4 + gcol;
            const float* g3 = table + (size_t)tk0.w * G4 + gcol;
#pragma unroll
            for (int gt = 0; gt < 4; gt++) {
                xgA[gt][0] = g0[gt * 128];
                xgA[gt][1] = g1[gt * 128];
                xgA[gt][2] = g2[gt * 128];
                xgA[gt][3] = g3[gt * 128];
            }
        }
        auto step0 = [&](int T, int cur, f32x4 (&xgc)[4], f32x4 (&xgn)[4]) {
            half8 a_h[4];
#pragma unroll
            for (int kc = 0; kc < 4; kc++)
                a_h[kc] = *(const half8*)&Hb[cur][rd_idx[kc]];
            const int Tn = (T + 1 < SS) ? T + 1 : T;
            const int4 tkn = *(const int4*)&tokL[Tn * 16 + 4 * qd];
            f32x4 p[4], q[4];
#pragma unroll
            for (int gt = 0; gt < 4; gt++) {
                f32x4 t = __builtin_amdgcn_mfma_f32_16x16x32_f16(
                    a_h[0], whh[gt][0], xgc[gt], 0, 0, 0);
                p[gt] = __builtin_amdgcn_mfma_f32_16x16x32_f16(
                    a_h[1], whh[gt][1], t, 0, 0, 0);
                f32x4 u = __builtin_amdgcn_mfma_f32_16x16x32_f16(
                    a_h[2], whh[gt][2], (f32x4){0.f, 0.f, 0.f, 0.f}, 0, 0, 0);
                q[gt] = __builtin_amdgcn_mfma_f32_16x16x32_f16(
                    a_h[3], whh[gt][3], u, 0, 0, 0);
            }
            {   // shadow: gather xg for T+1 (overlaps MFMA execution)
                const float* g0 = table + (size_t)tkn.x * G4 + gcol;
                const float* g1 = table + (size_t)tkn.y * G4 + gcol;
                const float* g2 = table + (size_t)tkn.z * G4 + gcol;
                const float* g3 = table + (size_t)tkn.w * G4 + gcol;
#pragma unroll
                for (int gt = 0; gt < 4; gt++) {
                    xgn[gt][0] = g0[gt * 128];
                    xgn[gt][1] = g1[gt * 128];
                    xgn[gt][2] = g2[gt * 128];
                    xgn[gt][3] = g3[gt * 128];
                }
            }
            finish(p, q, cur ^ 1);
        };
        for (int c = 0; c < NCH; c++) {
            for (int tt = 0; tt < CH; tt += 2) {
                step0(c * CH + tt,     0, xgA, xgB);
                step0(c * CH + tt + 1, 1, xgB, xgA);
            }
            signal(c);
        }
    } else {
        wait_src(2 * CH);
        const _Float16* xbase = xin + ((size_t)B0 + colD) * HH + qd * 8;
        // prologue: accXA = bias + Wih·x(0); xcur = x(1)
        half8 xcur[4];
        f32x4 accXA[4], accXB[4];
#pragma unroll
        for (int kc = 0; kc < 4; kc++)
            xcur[kc] = *(const half8*)(xbase + (size_t)0 * BB * HH + kc * 32);
#pragma unroll
        for (int gt = 0; gt < 4; gt++) {
            f32x4 t = bias_frag[gt];
#pragma unroll
            for (int kc = 0; kc < 4; kc++)
                t = __builtin_amdgcn_mfma_f32_16x16x32_f16(
                    xcur[kc], wih[gt][kc], t, 0, 0, 0);
            accXA[gt] = t;
        }
#pragma unroll
        for (int kc = 0; kc < 4; kc++)
            xcur[kc] = *(const half8*)(xbase + (size_t)1 * BB * HH + kc * 32);

        // step T: h-chain (2+2) from accXc; shadow computes accXn = bias +
        // Wih·x(T+1) from xcur, then refills xcur = x(T+2).
        auto stepK = [&](int T, int cur, f32x4 (&accXc)[4], f32x4 (&accXn)[4]) {
            half8 a_h[4];
#pragma unroll
            for (int kc = 0; kc < 4; kc++)
                a_h[kc] = *(const half8*)&Hb[cur][rd_idx[kc]];
            f32x4 p[4], q[4];
#pragma unroll
            for (int gt = 0; gt < 4; gt++) {
                f32x4 t = __builtin_amdgcn_mfma_f32_16x16x32_f16(
                    a_h[0], whh[gt][0], accXc[gt], 0, 0, 0);
                p[gt] = __builtin_amdgcn_mfma_f32_16x16x32_f16(
                    a_h[1], whh[gt][1], t, 0, 0, 0);
                f32x4 u = __builtin_amdgcn_mfma_f32_16x16x32_f16(
                    a_h[2], whh[gt][2], (f32x4){0.f, 0.f, 0.f, 0.f}, 0, 0, 0);
                q[gt] = __builtin_amdgcn_mfma_f32_16x16x32_f16(
                    a_h[3], whh[gt][3], u, 0, 0, 0);
            }
            // shadow: x-projection for T+1
#pragma unroll
            for (int gt = 0; gt < 4; gt++) {
                f32x4 t = bias_frag[gt];
#pragma unroll
                for (int kc = 0; kc < 4; kc++)
                    t = __builtin_amdgcn_mfma_f32_16x16x32_f16(
                        xcur[kc], wih[gt][kc], t, 0, 0, 0);
                accXn[gt] = t;
            }
            {   // refill xcur = x(T+2)
                const size_t tf =
                    (T + 2 < SS) ? (size_t)(T + 2) : (size_t)(SS - 1);
#pragma unroll
                for (int kc = 0; kc < 4; kc++)
                    xcur[kc] = *(const half8*)(xbase + tf * BB * HH + kc * 32);
            }
            finish(p, q, cur ^ 1);
        };
        for (int c = 0; c < NCH; c++) {
            if (c) {
                const int tgt = (c + 2) * CH;
                wait_src(tgt > SS ? SS : tgt);
            }
            for (int tt = 0; tt < CH; tt += 2) {
                stepK(c * CH + tt,     0, accXA, accXB);
                stepK(c * CH + tt + 1, 1, accXB, accXA);
            }
            if (layer == 1) signal(c);
        }
    }
}

// ---- FC head via MFMA: out[m][n] = h2[m]·fcW[n] + fcb[n] ------------------
__global__ __launch_bounds__(256) void fc_mfma(
    const _Float16* __restrict__ h2, const _Float16* __restrict__ pfcW,
    const float* __restrict__ fcb, float* __restrict__ out)
{
    const int tid = threadIdx.x, wv = tid >> 6, l = tid & 63;
    const int colD = l & 15, qd = l >> 4;
    const size_t m0 = (size_t)blockIdx.x * 64 + wv * 16;
    half8 a[4];
#pragma unroll
    for (int kc = 0; kc < 4; kc++)
        a[kc] = *(const half8*)(h2 + (m0 + colD) * HH + kc * 32 + qd * 8);
    float fcb_r[18];
#pragma unroll
    for (int nt = 0; nt < 18; nt++) fcb_r[nt] = fcb[nt * 16 + colD];
#pragma unroll
    for (int nt = 0; nt < 18; nt++) {
        f32x4 acc = {0.f, 0.f, 0.f, 0.f};
#pragma unroll
        for (int kc = 0; kc < 4; kc++) {
            const half8 b = *(const half8*)(pfcW + (((nt * 4 + kc) << 6) + l) * 8);
            acc = __builtin_amdgcn_mfma_f32_16x16x32_f16(a[kc], b, acc, 0, 0, 0);
        }
#pragma unroll
        for (int r = 0; r < 4; r++)
            out[(m0 + 4 * qd + r) * VV + nt * 16 + colD] = acc[r] + fcb_r[nt];
    }
}

extern "C" void kernel_launch(void* const* d_in, const int* in_sizes, int n_in,
                              void* d_out, int out_size, void* d_ws, size_t ws_size,
                              hipStream_t stream)
{
    (void)in_sizes; (void)n_in; (void)ws_size;
    const int*   text = (const int*)  d_in[0];
    const float* emb  = (const float*)d_in[1];
    const float* fcW  = (const float*)d_in[2];
    const float* fcb  = (const float*)d_in[3];
    const float* Wih0 = (const float*)d_in[4];
    const float* Whh0 = (const float*)d_in[5];
    const float* bih0 = (const float*)d_in[6];
    const float* bhh0 = (const float*)d_in[7];
    const float* Wih1 = (const float*)d_in[8];
    const float* Whh1 = (const float*)d_in[9];
    const float* bih1 = (const float*)d_in[10];
    const float* bhh1 = (const float*)d_in[11];
    const float* Wih2 = (const float*)d_in[12];
    const float* Whh2 = (const float*)d_in[13];
    const float* bih2 = (const float*)d_in[14];
    const float* bhh2 = (const float*)d_in[15];
    float* out = (float*)d_out;

    float* table = (float*)d_ws;
    _Float16* hX = (_Float16*)((char*)d_ws + 589824);
    _Float16* hY = hX + (size_t)SS * BB * HH;
    _Float16* pfcW = (_Float16*)d_ws;
    int* prog = ((int*)d_out) + ((size_t)out_size - 64);  // tail of out

    hipMemsetAsync(prog, 0, 64 * sizeof(int), stream);
    proj_kernel<<<VV, 512, 0, stream>>>(emb, Wih0, bih0, bhh0, table);
    lstm_pipe<<<48, 512, 0, stream>>>(text, table, Whh0,
                                      Wih1, Whh1, bih1, bhh1,
                                      Wih2, Whh2, bih2, bhh2,
                                      hX, hY, prog);
    pack_fc<<<144, 256, 0, stream>>>(fcW, pfcW);
    fc_mfma<<<4096, 256, 0, stream>>>(hX, pfcW, fcb, out);
}